// Round 1
// baseline (558.667 us; speedup 1.0000x reference)
//
#include <hip/hip_runtime.h>

#define C_IN 10
#define C_OUT 64
#define NUM_PILLARS 600000
#define BN_EPS 1e-3f

// ---------------------------------------------------------------------------
// Kernel 1: zero the output (600000 x 64 fp32 = 38.4M floats).
// Must run every launch: harness poisons d_out once and never re-poisons.
// ---------------------------------------------------------------------------
__global__ __launch_bounds__(256) void zero_out_kernel(float4* __restrict__ out4, int n4) {
    int i = blockIdx.x * blockDim.x + threadIdx.x;
    int stride = gridDim.x * blockDim.x;
    float4 z = make_float4(0.f, 0.f, 0.f, 0.f);
    for (int j = i; j < n4; j += stride) out4[j] = z;
}

// ---------------------------------------------------------------------------
// Kernel 2: fused Linear(10->64, no bias) + BN(eval) + ReLU + scatter-max.
// One wave per point; lane = output channel (C_OUT == 64 == wavefront size).
// ReLU output >= 0, so uint atomicMax on the float bit pattern == float max,
// and the 0.0f init handles empty pillars exactly like the reference.
// ---------------------------------------------------------------------------
__global__ __launch_bounds__(256) void pillar_scatter_kernel(
    const float* __restrict__ pts,      // (N, 10)
    const int*   __restrict__ idx,      // (N,)
    const float* __restrict__ W,        // (10, 64) row-major
    const float* __restrict__ gamma,    // (64,)
    const float* __restrict__ beta,     // (64,)
    const float* __restrict__ mean,     // (64,)
    const float* __restrict__ var,      // (64,)
    unsigned int* __restrict__ out,     // (NUM_PILLARS, 64) as uint bits
    int npoints)
{
    const int lane = threadIdx.x & 63;

    // Per-lane column of W (10 regs) + folded BN affine (2 regs), loaded once.
    float w[C_IN];
#pragma unroll
    for (int j = 0; j < C_IN; ++j) w[j] = W[j * C_OUT + lane];
    const float scale = gamma[lane] * rsqrtf(var[lane] + BN_EPS);
    const float shift = fmaf(-mean[lane], scale, beta[lane]);

    const int wave_id = (blockIdx.x * blockDim.x + threadIdx.x) >> 6;
    const int nwaves  = (gridDim.x * blockDim.x) >> 6;

    for (int p = wave_id; p < npoints; p += nwaves) {
        const float* f = pts + (size_t)p * C_IN;  // wave-uniform address
        float h = 0.f;
#pragma unroll
        for (int j = 0; j < C_IN; ++j) h = fmaf(f[j], w[j], h);
        h = fmaf(h, scale, shift);   // BN eval
        h = fmaxf(h, 0.f);           // ReLU  (>= 0)
        const int pid = idx[p];      // wave-uniform
        atomicMax(&out[(size_t)pid * C_OUT + lane], __float_as_uint(h));
    }
}

extern "C" void kernel_launch(void* const* d_in, const int* in_sizes, int n_in,
                              void* d_out, int out_size, void* d_ws, size_t ws_size,
                              hipStream_t stream) {
    const float* pts   = (const float*)d_in[0];
    const int*   idx   = (const int*)  d_in[1];
    const float* W     = (const float*)d_in[2];
    const float* gamma = (const float*)d_in[3];
    const float* beta  = (const float*)d_in[4];
    const float* mean  = (const float*)d_in[5];
    const float* var   = (const float*)d_in[6];

    const int npoints = in_sizes[0] / C_IN;   // 3,000,000

    // 1) zero output
    int n4 = out_size / 4;                     // 38.4M / 4
    zero_out_kernel<<<2048, 256, 0, stream>>>((float4*)d_out, n4);

    // 2) fused MLP + scatter-max
    // persistent grid: 2048 blocks x 4 waves = 8192 waves, ~366 points each
    pillar_scatter_kernel<<<2048, 256, 0, stream>>>(
        pts, idx, W, gamma, beta, mean, var, (unsigned int*)d_out, npoints);
}